// Round 2
// baseline (1193.540 us; speedup 1.0000x reference)
//
#include <hip/hip_runtime.h>
#include <stdint.h>
#include <stddef.h>

#define NQS 8192
#define NKS 8192
#define DS  256

typedef _Float16 half8 __attribute__((ext_vector_type(8)));
typedef float floatx4 __attribute__((ext_vector_type(4)));

#define MFMA_F16(A,B,C) __builtin_amdgcn_mfma_f32_16x16x32_f16(A,B,C,0,0,0)

// 16-lane butterfly reductions via DPP (DPP "row" = 16 lanes, gfx9 lineage).
__device__ __forceinline__ float red16_max(float x){
  x = fmaxf(x, __builtin_bit_cast(float, __builtin_amdgcn_update_dpp(0, __builtin_bit_cast(int, x), 0xB1, 0xF, 0xF, true)));
  x = fmaxf(x, __builtin_bit_cast(float, __builtin_amdgcn_update_dpp(0, __builtin_bit_cast(int, x), 0x4E, 0xF, 0xF, true)));
  x = fmaxf(x, __builtin_bit_cast(float, __builtin_amdgcn_update_dpp(0, __builtin_bit_cast(int, x), 0x141, 0xF, 0xF, true)));
  x = fmaxf(x, __builtin_bit_cast(float, __builtin_amdgcn_update_dpp(0, __builtin_bit_cast(int, x), 0x140, 0xF, 0xF, true)));
  return x;
}
__device__ __forceinline__ float red16_sum(float x){
  x += __builtin_bit_cast(float, __builtin_amdgcn_update_dpp(0, __builtin_bit_cast(int, x), 0xB1, 0xF, 0xF, true));
  x += __builtin_bit_cast(float, __builtin_amdgcn_update_dpp(0, __builtin_bit_cast(int, x), 0x4E, 0xF, 0xF, true));
  x += __builtin_bit_cast(float, __builtin_amdgcn_update_dpp(0, __builtin_bit_cast(int, x), 0x141, 0xF, 0xF, true));
  x += __builtin_bit_cast(float, __builtin_amdgcn_update_dpp(0, __builtin_bit_cast(int, x), 0x140, 0xF, 0xF, true));
  return x;
}

// ---------- mask dtype detection ----------
// int32 0/1 mask: every 4B word is 0 or 1 -> OR <= 1.
// uint8 bool mask: words pack 4 bools -> OR will have high-byte bits set
// (P[all 16384 words in {0,1}] = (1/8)^16384 ~ 0).
__global__ void detect_mask(const uint32_t* __restrict__ M, uint32_t* __restrict__ flag){
  __shared__ uint32_t s[256];
  uint32_t acc = 0;
  for (int i = threadIdx.x; i < 16384; i += 256) acc |= M[i];
  s[threadIdx.x] = acc;
  __syncthreads();
  if (threadIdx.x == 0){
    uint32_t t = 0;
    for (int i = 0; i < 256; i++) t |= s[i];
    *flag = (t > 1u) ? 1u : 0u;   // 1 = bytes (uint8), 0 = int32
  }
}

// ---------- mask bit-pack: Mp[row*256 + k/32] bit (k%32) ----------
__global__ void pack_mask(const uint8_t* __restrict__ M8,
                          const uint32_t* __restrict__ flag,
                          uint32_t* __restrict__ Mp){
  const uint32_t* M32 = (const uint32_t*)M8;
  const bool by = (*flag != 0u);
  int tid  = blockIdx.x*256 + threadIdx.x;   // 1024 blocks
  int wid  = tid >> 6;                       // 4096 waves
  int lane = tid & 63;
  #pragma unroll 1
  for (int it = 0; it < 256; ++it){
    size_t e = ((size_t)(it*4096 + wid))*64 + lane;  // covers 2^26 elements
    uint32_t v = by ? (uint32_t)M8[e] : M32[e];
    uint64_t b = __ballot(v != 0u);
    if (lane == 0){
      uint2 w; w.x = (uint32_t)b; w.y = (uint32_t)(b >> 32);
      *(uint2*)(Mp + (e >> 5)) = w;
    }
  }
}

// ---------- conversion pre-passes ----------
__global__ void cvt_q(const float* __restrict__ Q, _Float16* __restrict__ Qh){
  size_t u = (size_t)blockIdx.x*256 + threadIdx.x;   // 262144 units of 8 elems
  const float4* src = (const float4*)(Q + u*8);
  float4 a = src[0], b = src[1];
  half8 h = {(_Float16)a.x,(_Float16)a.y,(_Float16)a.z,(_Float16)a.w,
             (_Float16)b.x,(_Float16)b.y,(_Float16)b.z,(_Float16)b.w};
  *(half8*)(Qh + u*8) = h;
}
// Kc: element K[key][d] at ((d>>3)*NKS + key)*8 + (d&7)
__global__ void cvt_k(const float* __restrict__ K, _Float16* __restrict__ Kc){
  int gid = blockIdx.x*256 + threadIdx.x;            // 65536 = 8 c4 * 8192 keys
  int c4 = gid >> 13, key = gid & 8191;
  const float4* base = (const float4*)(K + (size_t)key*DS + c4*32);
  float4 f[8];
  #pragma unroll
  for (int j=0;j<8;j++) f[j] = base[j];
  #pragma unroll
  for (int cc=0; cc<4; cc++){
    float4 a=f[cc*2], b=f[cc*2+1];
    half8 h = {(_Float16)a.x,(_Float16)a.y,(_Float16)a.z,(_Float16)a.w,
               (_Float16)b.x,(_Float16)b.y,(_Float16)b.z,(_Float16)b.w};
    *(half8*)(Kc + ((size_t)(c4*4+cc)*NKS + key)*8) = h;
  }
}
// Vc: element V[key][d] at ((key>>3)*DS + d)*8 + (key&7)
__global__ void cvt_v(const float* __restrict__ V, _Float16* __restrict__ Vc){
  int gid = blockIdx.x*256 + threadIdx.x;            // 262144 = 1024 kc * 256 d
  int kc = gid >> 8, d = gid & 255;
  half8 h;
  #pragma unroll
  for (int j=0;j<8;j++) h[j] = (_Float16)V[(size_t)(kc*8+j)*DS + d];
  *(half8*)(Vc + (size_t)gid*8) = h;
}

// ---------- main flash-attention kernel ----------
__global__ __launch_bounds__(512, 2) void attn_fwd(
  const _Float16* __restrict__ Qh, const _Float16* __restrict__ Kc,
  const _Float16* __restrict__ Vc, const uint32_t* __restrict__ Mp,
  float* __restrict__ Out)
{
  __shared__ _Float16 Plds[8][1280];   // per-wave 32x32 P tile, row stride 40 f16
  __shared__ float Ocomb[32*256];
  __shared__ float Mcomb[32];
  __shared__ float Lcomb[32];

  const int tid  = threadIdx.x;
  const int w    = tid >> 6;
  const int lane = tid & 63;
  const int quad = lane >> 4;
  const int l15  = lane & 15;
  const int rb   = blockIdx.x << 5;

  const float kLog = 0.09016844005556021f;  // (1/16) * log2(e)
  const float ZM   = -3.0e38f;              // masked sentinel (NaN-proof)

  // Q fragments: A-layout m=l15, k=quad*8+j
  half8 qf[2][8];
  #pragma unroll
  for (int mi=0;mi<2;mi++)
    #pragma unroll
    for (int ks=0;ks<8;ks++)
      qf[mi][ks] = *(const half8*)(Qh + (size_t)(rb + mi*16 + l15)*DS + ks*32 + quad*8);

  floatx4 O[2][16];
  #pragma unroll
  for (int mi=0;mi<2;mi++)
    #pragma unroll
    for (int n=0;n<16;n++) O[mi][n] = (floatx4){0.f,0.f,0.f,0.f};

  float mst[2][4], lst[2][4];
  #pragma unroll
  for (int mi=0;mi<2;mi++)
    #pragma unroll
    for (int r=0;r<4;r++){ mst[mi][r]=-1e30f; lst[mi][r]=0.f; }

  _Float16* myP = &Plds[w][0];

  for (int it=0; it<32; ++it){
    const int k0 = (w + (it<<3)) << 5;

    // packed mask: word row*256 + k0/32; bit l15 -> key k0+l15, bit 16+l15 -> key k0+16+l15
    uint32_t mwv[2][4];
    #pragma unroll
    for (int mi=0;mi<2;mi++)
      #pragma unroll
      for (int r=0;r<4;r++)
        mwv[mi][r] = Mp[(size_t)(rb + mi*16 + quad*4 + r)*(NKS/32) + (k0 >> 5)];

    // S = Q K^T (fp32 accum)
    floatx4 Sc[2][2];
    #pragma unroll
    for (int mi=0;mi<2;mi++){ Sc[mi][0]=(floatx4){0,0,0,0}; Sc[mi][1]=(floatx4){0,0,0,0}; }
    #pragma unroll
    for (int n=0;n<2;n++){
      #pragma unroll
      for (int ks=0;ks<8;ks++){
        half8 kb = *(const half8*)(Kc + ((size_t)(ks*4+quad)*NKS + (k0 + n*16 + l15))*8);
        Sc[0][n] = MFMA_F16(qf[0][ks], kb, Sc[0][n]);
        Sc[1][n] = MFMA_F16(qf[1][ks], kb, Sc[1][n]);
      }
    }

    // online softmax (exp2 domain); C-layout row = quad*4+r, col = l15
    float alpha[2][4];
    bool need = false;
    #pragma unroll
    for (int mi=0;mi<2;mi++){
      #pragma unroll
      for (int r=0;r<4;r++){
        bool b0 = (mwv[mi][r] >> l15) & 1u;
        bool b1 = (mwv[mi][r] >> (16 + l15)) & 1u;
        float z0 = b0 ? Sc[mi][0][r]*kLog : ZM;
        float z1 = b1 ? Sc[mi][1][r]*kLog : ZM;
        float zm = red16_max(fmaxf(z0,z1));
        float mold = mst[mi][r];
        float mnew = fmaxf(mold, zm);
        float a  = __builtin_amdgcn_exp2f(mold - mnew);
        float p0 = __builtin_amdgcn_exp2f(z0 - mnew);
        float p1 = __builtin_amdgcn_exp2f(z1 - mnew);
        float ps = red16_sum(p0 + p1);
        mst[mi][r] = mnew;
        lst[mi][r] = lst[mi][r]*a + ps;
        alpha[mi][r] = a;
        need |= (a != 1.0f);
        int row = mi*16 + quad*4 + r;
        myP[row*40 + l15]      = (_Float16)p0;
        myP[row*40 + 16 + l15] = (_Float16)p1;
      }
    }

    if (__ballot(need) != 0ull){
      #pragma unroll
      for (int mi=0;mi<2;mi++)
        #pragma unroll
        for (int n=0;n<16;n++)
          #pragma unroll
          for (int r=0;r<4;r++)
            O[mi][n][r] *= alpha[mi][r];
    }

    __syncthreads();  // order P writes before A-frag reads

    // P A-frags: m=l15, k=quad*8+j  (stride 40 f16 = 80 B, 16B aligned)
    half8 pa0 = *(const half8*)(myP + (size_t)l15*40      + quad*8);
    half8 pa1 = *(const half8*)(myP + (size_t)(16+l15)*40 + quad*8);

    // O += P V : B-frag key=quad*8+j, d=n*16+l15
    #pragma unroll
    for (int n=0;n<16;n++){
      half8 vb = *(const half8*)(Vc + ((size_t)((k0>>3)+quad)*DS + n*16 + l15)*8);
      O[0][n] = MFMA_F16(pa0, vb, O[0][n]);
      O[1][n] = MFMA_F16(pa1, vb, O[1][n]);
    }
  }

  // serial merge of the 8 per-wave partials
  #pragma unroll 1
  for (int s=0; s<8; ++s){
    if (w == s){
      if (s == 0){
        #pragma unroll
        for (int mi=0;mi<2;mi++)
          #pragma unroll
          for (int r=0;r<4;r++){
            int row = mi*16 + quad*4 + r;
            if (l15 == 0){ Mcomb[row] = mst[mi][r]; Lcomb[row] = lst[mi][r]; }
            #pragma unroll
            for (int n=0;n<16;n++)
              Ocomb[row*256 + n*16 + l15] = O[mi][n][r];
          }
      } else {
        #pragma unroll
        for (int mi=0;mi<2;mi++)
          #pragma unroll
          for (int r=0;r<4;r++){
            int row = mi*16 + quad*4 + r;
            float mc = Mcomb[row], lc = Lcomb[row];
            float mw = mst[mi][r], lw = lst[mi][r];
            float mn = fmaxf(mc, mw);
            float ac = __builtin_amdgcn_exp2f(mc - mn);
            float aw = __builtin_amdgcn_exp2f(mw - mn);
            if (l15 == 0){ Mcomb[row] = mn; Lcomb[row] = lc*ac + lw*aw; }
            #pragma unroll
            for (int n=0;n<16;n++){
              int idx = row*256 + n*16 + l15;
              Ocomb[idx] = Ocomb[idx]*ac + O[mi][n][r]*aw;
            }
          }
      }
    }
    __syncthreads();
  }

  // normalize + store (coalesced)
  {
    int row = tid >> 4;
    int cb  = (tid & 15) << 2;
    float linv = 1.0f / Lcomb[row];
    #pragma unroll
    for (int j=0;j<4;j++){
      int col = cb + j*64;
      float4 v = *(float4*)&Ocomb[row*256 + col];
      v.x *= linv; v.y *= linv; v.z *= linv; v.w *= linv;
      *(float4*)(Out + (size_t)(rb+row)*DS + col) = v;
    }
  }
}

extern "C" void kernel_launch(void* const* d_in, const int* in_sizes, int n_in,
                              void* d_out, int out_size, void* d_ws, size_t ws_size,
                              hipStream_t stream){
  (void)in_sizes; (void)n_in; (void)out_size; (void)ws_size;
  const float*   K = (const float*)d_in[0];
  const float*   V = (const float*)d_in[1];
  const float*   Q = (const float*)d_in[2];
  const uint8_t* M = (const uint8_t*)d_in[3];
  float* Out = (float*)d_out;

  _Float16* Qh = (_Float16*)d_ws;                         // 4 MiB
  _Float16* Kc = Qh + (size_t)NQS*DS;                     // 4 MiB
  _Float16* Vc = Kc + (size_t)NKS*DS;                     // 4 MiB
  uint32_t* Mp = (uint32_t*)(Vc + (size_t)NKS*DS);        // 8 MiB (bit-packed mask)
  uint32_t* flag = Mp + (size_t)NQS*(NKS/32);             // 4 B

  hipLaunchKernelGGL(detect_mask, dim3(1),    dim3(256), 0, stream, (const uint32_t*)M, flag);
  hipLaunchKernelGGL(pack_mask,   dim3(1024), dim3(256), 0, stream, M, flag, Mp);
  hipLaunchKernelGGL(cvt_q, dim3(1024), dim3(256), 0, stream, Q, Qh);
  hipLaunchKernelGGL(cvt_k, dim3(256),  dim3(256), 0, stream, K, Kc);
  hipLaunchKernelGGL(cvt_v, dim3(1024), dim3(256), 0, stream, V, Vc);
  hipLaunchKernelGGL(attn_fwd, dim3(256), dim3(512), 0, stream, Qh, Kc, Vc, Mp, Out);
}

// Round 3
// 806.554 us; speedup vs baseline: 1.4798x; 1.4798x over previous
//
#include <hip/hip_runtime.h>
#include <stdint.h>
#include <stddef.h>

#define NQS 8192
#define NKS 8192
#define DS  256

typedef _Float16 half8 __attribute__((ext_vector_type(8)));
typedef float floatx4 __attribute__((ext_vector_type(4)));

#define MFMA_F16(A,B,C) __builtin_amdgcn_mfma_f32_16x16x32_f16(A,B,C,0,0,0)

// 16-lane butterfly reductions via DPP.
__device__ __forceinline__ float red16_max(float x){
  x = fmaxf(x, __builtin_bit_cast(float, __builtin_amdgcn_update_dpp(0, __builtin_bit_cast(int, x), 0xB1, 0xF, 0xF, true)));
  x = fmaxf(x, __builtin_bit_cast(float, __builtin_amdgcn_update_dpp(0, __builtin_bit_cast(int, x), 0x4E, 0xF, 0xF, true)));
  x = fmaxf(x, __builtin_bit_cast(float, __builtin_amdgcn_update_dpp(0, __builtin_bit_cast(int, x), 0x141, 0xF, 0xF, true)));
  x = fmaxf(x, __builtin_bit_cast(float, __builtin_amdgcn_update_dpp(0, __builtin_bit_cast(int, x), 0x140, 0xF, 0xF, true)));
  return x;
}
__device__ __forceinline__ float red16_sum(float x){
  x += __builtin_bit_cast(float, __builtin_amdgcn_update_dpp(0, __builtin_bit_cast(int, x), 0xB1, 0xF, 0xF, true));
  x += __builtin_bit_cast(float, __builtin_amdgcn_update_dpp(0, __builtin_bit_cast(int, x), 0x4E, 0xF, 0xF, true));
  x += __builtin_bit_cast(float, __builtin_amdgcn_update_dpp(0, __builtin_bit_cast(int, x), 0x141, 0xF, 0xF, true));
  x += __builtin_bit_cast(float, __builtin_amdgcn_update_dpp(0, __builtin_bit_cast(int, x), 0x140, 0xF, 0xF, true));
  return x;
}

// ---------- mask dtype detection (int32 0/1 words OR to <=1; bytes don't) ----------
__global__ void detect_mask(const uint32_t* __restrict__ M, uint32_t* __restrict__ flag){
  __shared__ uint32_t s[256];
  uint32_t acc = 0;
  for (int i = threadIdx.x; i < 16384; i += 256) acc |= M[i];
  s[threadIdx.x] = acc;
  __syncthreads();
  if (threadIdx.x == 0){
    uint32_t t = 0;
    for (int i = 0; i < 256; i++) t |= s[i];
    *flag = (t > 1u) ? 1u : 0u;   // 1 = bytes (uint8), 0 = int32
  }
}

// ---------- vectorized mask bit-pack: thread t -> word t (keys t*32..t*32+31) ----------
__global__ void pack_mask(const uint8_t* __restrict__ M8,
                          const uint32_t* __restrict__ flag,
                          uint32_t* __restrict__ Mp){
  size_t t = (size_t)blockIdx.x*256 + threadIdx.x;   // 2,097,152 threads
  uint32_t w = 0;
  if (*flag){  // byte mode: 32 B per thread
    const uint4* p = (const uint4*)(M8 + (t << 5));
    uint4 a = p[0], b = p[1];
    uint32_t v[8] = {a.x,a.y,a.z,a.w,b.x,b.y,b.z,b.w};
    #pragma unroll
    for (int j=0;j<8;j++){
      w |= (((v[j]      ) & 0xFFu) ? 1u:0u) << (j*4+0);
      w |= (((v[j] >>  8) & 0xFFu) ? 1u:0u) << (j*4+1);
      w |= (((v[j] >> 16) & 0xFFu) ? 1u:0u) << (j*4+2);
      w |= (((v[j] >> 24)        ) ? 1u:0u) << (j*4+3);
    }
  } else {     // int32 mode: 128 B per thread
    const uint4* p = (const uint4*)M8 + (t << 3);
    #pragma unroll
    for (int j=0;j<8;j++){
      uint4 v = p[j];
      w |= (v.x?1u:0u) << (j*4+0);
      w |= (v.y?1u:0u) << (j*4+1);
      w |= (v.z?1u:0u) << (j*4+2);
      w |= (v.w?1u:0u) << (j*4+3);
    }
  }
  Mp[t] = w;
}

// ---------- K/V conversion ----------
// Kc: element K[key][d] at ((d>>3)*NKS + key)*8 + (d&7)
__global__ void cvt_k(const float* __restrict__ K, _Float16* __restrict__ Kc){
  int gid = blockIdx.x*256 + threadIdx.x;            // 65536
  int c4 = gid >> 13, key = gid & 8191;
  const float4* base = (const float4*)(K + (size_t)key*DS + c4*32);
  float4 f[8];
  #pragma unroll
  for (int j=0;j<8;j++) f[j] = base[j];
  #pragma unroll
  for (int cc=0; cc<4; cc++){
    float4 a=f[cc*2], b=f[cc*2+1];
    half8 h = {(_Float16)a.x,(_Float16)a.y,(_Float16)a.z,(_Float16)a.w,
               (_Float16)b.x,(_Float16)b.y,(_Float16)b.z,(_Float16)b.w};
    *(half8*)(Kc + ((size_t)(c4*4+cc)*NKS + key)*8) = h;
  }
}
// Vc: element V[key][d] at ((key>>3)*DS + d)*8 + (key&7)
__global__ void cvt_v(const float* __restrict__ V, _Float16* __restrict__ Vc){
  int gid = blockIdx.x*256 + threadIdx.x;            // 262144
  int kc = gid >> 8, d = gid & 255;
  half8 h;
  #pragma unroll
  for (int j=0;j<8;j++) h[j] = (_Float16)V[(size_t)(kc*8+j)*DS + d];
  *(half8*)(Vc + (size_t)gid*8) = h;
}

// ---------- main flash kernel ----------
// grid 1024 = 256 row-groups x 4 key-quarters (kh = b&3 -> per-XCD K/V quarter fits L2).
// block = 4 waves, all on the same 32 rows; waves split the 2048-key quarter 4 ways,
// NO barrier in the hot loop; 4-partial merge via LDS at the end; block partial -> ws.
__global__ __launch_bounds__(256, 2) void attn_fwd(
  const float* __restrict__ Qf, const _Float16* __restrict__ Kc,
  const _Float16* __restrict__ Vc, const uint32_t* __restrict__ Mp,
  float* __restrict__ Op, float* __restrict__ Mo, float* __restrict__ Lo)
{
  __shared__ _Float16 Plds[4][1280];   // per-wave 32x32 P tile, row stride 40
  __shared__ float Ocomb[32*256];
  __shared__ float Mcomb[32];
  __shared__ float Lcomb[32];

  const int tid  = threadIdx.x;
  const int w    = tid >> 6;
  const int lane = tid & 63;
  const int quad = lane >> 4;
  const int l15  = lane & 15;
  const int b    = blockIdx.x;
  const int g32  = b >> 2;           // row-group of 32
  const int kh   = b & 3;            // key quarter (XCD-affine)
  const int rb   = g32 << 5;
  const int kbase = kh << 11;        // *2048

  const float kLog = 0.09016844005556021f;  // (1/16) * log2(e)
  const float ZM   = -3.0e38f;

  // Q fragments (fp32 -> f16 in-kernel): A-layout m=l15, k=quad*8+j
  half8 qf[2][8];
  #pragma unroll
  for (int mi=0;mi<2;mi++){
    const float* qrow = Qf + (size_t)(rb + mi*16 + l15)*DS;
    #pragma unroll
    for (int ks=0;ks<8;ks++){
      const float4* s = (const float4*)(qrow + ks*32 + quad*8);
      float4 x = s[0], y = s[1];
      qf[mi][ks] = (half8){(_Float16)x.x,(_Float16)x.y,(_Float16)x.z,(_Float16)x.w,
                           (_Float16)y.x,(_Float16)y.y,(_Float16)y.z,(_Float16)y.w};
    }
  }

  floatx4 O[2][16];
  #pragma unroll
  for (int mi=0;mi<2;mi++)
    #pragma unroll
    for (int n=0;n<16;n++) O[mi][n] = (floatx4){0.f,0.f,0.f,0.f};

  float mst[2][4], lst[2][4];
  #pragma unroll
  for (int mi=0;mi<2;mi++)
    #pragma unroll
    for (int r=0;r<4;r++){ mst[mi][r]=-1e30f; lst[mi][r]=0.f; }

  _Float16* myP = &Plds[w][0];

  #pragma unroll 1
  for (int it=0; it<16; ++it){
    const int k0 = kbase + (((it<<2) + w) << 5);   // this wave's 32-key tile

    uint32_t mwv[2][4];
    #pragma unroll
    for (int mi=0;mi<2;mi++)
      #pragma unroll
      for (int r=0;r<4;r++)
        mwv[mi][r] = Mp[(size_t)(rb + mi*16 + quad*4 + r)*(NKS/32) + (k0 >> 5)];

    floatx4 Sc[2][2];
    #pragma unroll
    for (int mi=0;mi<2;mi++){ Sc[mi][0]=(floatx4){0,0,0,0}; Sc[mi][1]=(floatx4){0,0,0,0}; }
    #pragma unroll
    for (int n=0;n<2;n++){
      #pragma unroll
      for (int ks=0;ks<8;ks++){
        half8 kb = *(const half8*)(Kc + ((size_t)(ks*4+quad)*NKS + (k0 + n*16 + l15))*8);
        Sc[0][n] = MFMA_F16(qf[0][ks], kb, Sc[0][n]);
        Sc[1][n] = MFMA_F16(qf[1][ks], kb, Sc[1][n]);
      }
    }

    float alpha[2][4];
    bool need = false;
    #pragma unroll
    for (int mi=0;mi<2;mi++){
      #pragma unroll
      for (int r=0;r<4;r++){
        bool b0 = (mwv[mi][r] >> l15) & 1u;
        bool b1 = (mwv[mi][r] >> (16 + l15)) & 1u;
        float z0 = b0 ? Sc[mi][0][r]*kLog : ZM;
        float z1 = b1 ? Sc[mi][1][r]*kLog : ZM;
        float zm = red16_max(fmaxf(z0,z1));
        float mold = mst[mi][r];
        float mnew = fmaxf(mold, zm);
        float a  = __builtin_amdgcn_exp2f(mold - mnew);
        float p0 = __builtin_amdgcn_exp2f(z0 - mnew);
        float p1 = __builtin_amdgcn_exp2f(z1 - mnew);
        float ps = red16_sum(p0 + p1);
        mst[mi][r] = mnew;
        lst[mi][r] = lst[mi][r]*a + ps;
        alpha[mi][r] = a;
        need |= (a != 1.0f);
        int row = mi*16 + quad*4 + r;
        myP[row*40 + l15]      = (_Float16)p0;
        myP[row*40 + 16 + l15] = (_Float16)p1;
      }
    }

    if (__ballot(need) != 0ull){
      #pragma unroll
      for (int mi=0;mi<2;mi++)
        #pragma unroll
        for (int n=0;n<16;n++)
          #pragma unroll
          for (int r=0;r<4;r++)
            O[mi][n][r] *= alpha[mi][r];
    }

    // per-wave LDS P round-trip; same-wave ordering handled by lgkmcnt (no barrier)
    half8 pa0 = *(const half8*)(myP + (size_t)l15*40      + quad*8);
    half8 pa1 = *(const half8*)(myP + (size_t)(16+l15)*40 + quad*8);

    #pragma unroll
    for (int n=0;n<16;n++){
      half8 vb = *(const half8*)(Vc + ((size_t)((k0>>3)+quad)*DS + n*16 + l15)*8);
      O[0][n] = MFMA_F16(pa0, vb, O[0][n]);
      O[1][n] = MFMA_F16(pa1, vb, O[1][n]);
    }
  }

  // ---- intra-block merge of 4 key-slice partials (end of kernel only) ----
  #pragma unroll 1
  for (int s=0; s<4; ++s){
    if (w == s){
      if (s == 0){
        #pragma unroll
        for (int mi=0;mi<2;mi++)
          #pragma unroll
          for (int r=0;r<4;r++){
            int row = mi*16 + quad*4 + r;
            if (l15 == 0){ Mcomb[row] = mst[mi][r]; Lcomb[row] = lst[mi][r]; }
            #pragma unroll
            for (int n=0;n<16;n++)
              Ocomb[row*256 + n*16 + l15] = O[mi][n][r];
          }
      } else {
        #pragma unroll
        for (int mi=0;mi<2;mi++)
          #pragma unroll
          for (int r=0;r<4;r++){
            int row = mi*16 + quad*4 + r;
            float mc = Mcomb[row], lc = Lcomb[row];
            float mw = mst[mi][r], lw = lst[mi][r];
            float mn = fmaxf(mc, mw);
            float ac = __builtin_amdgcn_exp2f(mc - mn);
            float aw = __builtin_amdgcn_exp2f(mw - mn);
            if (l15 == 0){ Mcomb[row] = mn; Lcomb[row] = lc*ac + lw*aw; }
            #pragma unroll
            for (int n=0;n<16;n++){
              int idx = row*256 + n*16 + l15;
              Ocomb[idx] = Ocomb[idx]*ac + O[mi][n][r]*aw;
            }
          }
      }
    }
    __syncthreads();
  }

  // ---- write block partial (unnormalized) to workspace, coalesced ----
  float* ob = Op + (size_t)b*8192;
  #pragma unroll
  for (int p=0;p<8;p++){
    int off = p*1024 + tid*4;
    *(float4*)(ob + off) = *(float4*)&Ocomb[off];
  }
  if (tid < 32){
    Mo[b*32 + tid] = Mcomb[tid];
    Lo[b*32 + tid] = Lcomb[tid];
  }
}

// ---------- cross-block combine of the 4 key-quarters ----------
__global__ void combine4(const float* __restrict__ Op, const float* __restrict__ Mo,
                         const float* __restrict__ Lo, float* __restrict__ Out){
  int gid = blockIdx.x*256 + threadIdx.x;   // 524288 threads, one float4 each
  int row = gid >> 6;
  int c4  = (gid & 63) << 2;
  int g32 = row >> 5, r = row & 31;

  float m[4], l[4];
  #pragma unroll
  for (int kh=0;kh<4;kh++){
    int blk = g32*4 + kh;
    m[kh] = Mo[blk*32 + r];
    l[kh] = Lo[blk*32 + r];
  }
  float mn = fmaxf(fmaxf(m[0],m[1]), fmaxf(m[2],m[3]));
  float lt = 0.f;
  float a[4];
  #pragma unroll
  for (int kh=0;kh<4;kh++){ a[kh] = __builtin_amdgcn_exp2f(m[kh]-mn); lt += l[kh]*a[kh]; }
  float li = 1.0f / lt;

  float4 acc = {0,0,0,0};
  #pragma unroll
  for (int kh=0;kh<4;kh++){
    int blk = g32*4 + kh;
    float4 o = *(const float4*)(Op + (size_t)blk*8192 + r*256 + c4);
    acc.x += o.x*a[kh]; acc.y += o.y*a[kh]; acc.z += o.z*a[kh]; acc.w += o.w*a[kh];
  }
  acc.x *= li; acc.y *= li; acc.z *= li; acc.w *= li;
  *(float4*)(Out + (size_t)row*DS + c4) = acc;
}

extern "C" void kernel_launch(void* const* d_in, const int* in_sizes, int n_in,
                              void* d_out, int out_size, void* d_ws, size_t ws_size,
                              hipStream_t stream){
  (void)in_sizes; (void)n_in; (void)out_size; (void)ws_size;
  const float*   K = (const float*)d_in[0];
  const float*   V = (const float*)d_in[1];
  const float*   Q = (const float*)d_in[2];
  const uint8_t* M = (const uint8_t*)d_in[3];
  float* Out = (float*)d_out;

  _Float16* Kc = (_Float16*)d_ws;                         // 4 MiB
  _Float16* Vc = Kc + (size_t)NKS*DS;                     // 4 MiB
  uint32_t* Mp = (uint32_t*)(Vc + (size_t)NKS*DS);        // 8 MiB
  float*    Op = (float*)(Mp + (size_t)NQS*(NKS/32));     // 32 MiB (1024 blocks x 32x256)
  float*    Mo = Op + (size_t)1024*8192;                  // 128 KiB
  float*    Lo = Mo + 1024*32;                            // 128 KiB
  uint32_t* flag = (uint32_t*)(Lo + 1024*32);             // 4 B

  hipLaunchKernelGGL(detect_mask, dim3(1),    dim3(256), 0, stream, (const uint32_t*)M, flag);
  hipLaunchKernelGGL(pack_mask,   dim3(8192), dim3(256), 0, stream, M, flag, Mp);
  hipLaunchKernelGGL(cvt_k, dim3(256),  dim3(256), 0, stream, K, Kc);
  hipLaunchKernelGGL(cvt_v, dim3(1024), dim3(256), 0, stream, V, Vc);
  hipLaunchKernelGGL(attn_fwd, dim3(1024), dim3(256), 0, stream, Q, Kc, Vc, Mp, Op, Mo, Lo);
  hipLaunchKernelGGL(combine4, dim3(2048), dim3(256), 0, stream, Op, Mo, Lo, Out);
}